// Round 7
// baseline (72.293 us; speedup 1.0000x reference)
//
#include <hip/hip_runtime.h>

#define WSZ    64
#define BLOCK  256
#define STRIDE 20            // dwords per LDS row: 16 data + 4 pad (even 4-bank-group spread)
#define INV2PI 0.15915494309189535f   // v_sin/v_cos take revolutions

__global__ __launch_bounds__(BLOCK) void sq_main(
    const float* __restrict__ x,
    const float* __restrict__ theta,
    const float* __restrict__ w,
    const float* __restrict__ bias,
    float* __restrict__ out)
{
    // Per-wave private x buffer: 64 rows x 20 dwords = 5120 B; 4 waves = 20 KB.
    // Shared coef table: 2 KB. Total 22.25 KB -> 7 blocks/CU = 28 waves/CU.
    __shared__ float  xs[4][WSZ * STRIDE];
    __shared__ float4 tA[WSZ];   // (m00, m01, m02, m10) of Rz(b)*Ry(a) Bloch matrix
    __shared__ float4 tB[WSZ];   // (m11, m12, m20, m22); m21 == 0

    const int tid  = threadIdx.x;
    const int lane = tid & 63;
    const int wid  = tid >> 6;
    const size_t wrow0 = (size_t)blockIdx.x * BLOCK + wid * 64;
    const float* xw = x + wrow0 * WSZ;
    float* ws = xs[wid];

    const float wv = w[0];       // uniform -> s_load, hoisted off the epilogue
    const float bv = bias[0];

    // ---- coef table: M = Rz(b)*Ry(a) = [cb*ca, -sb, cb*sa; sb*ca, cb, sb*sa; -sa, 0, ca]
    if (tid < WSZ) {
        float2 th = reinterpret_cast<const float2*>(theta)[tid];
        float sa = __builtin_amdgcn_sinf(th.x * INV2PI);
        float ca = __builtin_amdgcn_cosf(th.x * INV2PI);
        float sb = __builtin_amdgcn_sinf(th.y * INV2PI);
        float cb = __builtin_amdgcn_cosf(th.y * INV2PI);
        tA[tid] = make_float4(cb * ca, -sb, cb * sa, sb * ca);
        tB[tid] = make_float4(cb, sb * sa, -sa, ca);
    }

    // ---- prefetch chunk 0 (16 cols): instr j covers rows j*16..j*16+15, 64B/row ----
    const int lrow  = lane >> 2;   // 0..15
    const int lslot = lane & 3;    // float4 slot within the 16-col chunk

    float4 stage[4];
    #pragma unroll
    for (int j = 0; j < 4; ++j)
        stage[j] = *reinterpret_cast<const float4*>(
            xw + (size_t)(j * 16 + lrow) * WSZ + lslot * 4);

    __syncthreads();   // coef table ready (only barrier in the kernel)

    float vx = 0.0f, vy = 0.0f, vz = 1.0f;

    #pragma unroll
    for (int c = 0; c < 4; ++c) {
        // store staged chunk c (ds_write_b128, even bank spread via stride 20)
        #pragma unroll
        for (int j = 0; j < 4; ++j)
            *reinterpret_cast<float4*>(&ws[(j * 16 + lrow) * STRIDE + lslot * 4]) = stage[j];

        // prefetch chunk c+1; flies under this chunk's compute (per-wave, no barrier)
        if (c < 3) {
            #pragma unroll
            for (int j = 0; j < 4; ++j)
                stage[j] = *reinterpret_cast<const float4*>(
                    xw + (size_t)(j * 16 + lrow) * WSZ + (c + 1) * 16 + lslot * 4);
        }

        // 16 steps; lane reads its own row (same-wave LDS ops are in-order -> race-free)
        #pragma unroll
        for (int c2 = 0; c2 < 4; ++c2) {
            float4 xv = *reinterpret_cast<const float4*>(&ws[lane * STRIDE + c2 * 4]);
            float xr[4] = {xv.x, xv.y, xv.z, xv.w};
            #pragma unroll
            for (int j = 0; j < 4; ++j) {
                const int t = c * 16 + c2 * 4 + j;   // compile-time step index
                float r  = xr[j] * INV2PI;
                float s  = __builtin_amdgcn_sinf(r);
                float co = __builtin_amdgcn_cosf(r);
                float4 A  = tA[t];                   // uniform ds_read_b128 broadcast
                float4 Bv = tB[t];
                float y1 = co * vy - s * vz;         // Rx(x_t)
                float z1 = s  * vy + co * vz;
                float nx = A.x  * vx + A.y  * y1 + A.z  * z1;
                float ny = A.w  * vx + Bv.x * y1 + Bv.y * z1;
                float nz = Bv.z * vx + Bv.w * z1;    // m21 == 0
                vx = nx; vy = ny; vz = nz;
            }
        }
    }

    out[wrow0 + lane] = vz * wv + bv;
}

extern "C" void kernel_launch(void* const* d_in, const int* in_sizes, int n_in,
                              void* d_out, int out_size, void* d_ws, size_t ws_size,
                              hipStream_t stream) {
    const float* x     = (const float*)d_in[0];
    const float* theta = (const float*)d_in[1];
    const float* w     = (const float*)d_in[2];
    const float* b     = (const float*)d_in[3];
    float* out = (float*)d_out;

    int nrows = out_size;                 // B = 524288 (divisible by 256)
    int grid  = nrows / BLOCK;            // 2048 blocks
    sq_main<<<grid, BLOCK, 0, stream>>>(x, theta, w, b, out);
}

// Round 8
// 38.247 us; speedup vs baseline: 1.8902x; 1.8902x over previous
//
#include <hip/hip_runtime.h>

#define WSZ    64
#define BLOCK  256
#define INV2PI 0.15915494309189535f   // v_sin/v_cos take revolutions

__global__ __launch_bounds__(BLOCK) void sq_main(
    const float* __restrict__ x,
    const float* __restrict__ theta,
    const float* __restrict__ w,
    const float* __restrict__ bias,
    float* __restrict__ out)
{
    // Only LDS: the 64-step coefficient table (2.25 KB). No x staging at all:
    // each thread streams its own 256B row via 16 float4 loads (2 cache lines,
    // fully consumed by this lane -> HBM traffic = 1x, zero LDS pipe cost).
    __shared__ float4 tA[WSZ];   // (m00, m01, m02, m10) of Rz(b)*Ry(a) Bloch matrix
    __shared__ float4 tB[WSZ];   // (m11, m12, m20, m22); m21 == 0

    const int tid = threadIdx.x;
    const size_t row = (size_t)blockIdx.x * BLOCK + tid;
    const float4* xr4 = reinterpret_cast<const float4*>(x + row * WSZ);

    const float wv = w[0];       // uniform -> s_load
    const float bv = bias[0];

    // ping-pong row buffers: at most 32 data dwords live, compile-time indexed
    float4 bufA[4], bufB[4];

    auto issue = [&](float4 (&b)[4], int g) {
        #pragma unroll
        for (int k = 0; k < 4; ++k) b[k] = xr4[g * 4 + k];
    };

    issue(bufA, 0);              // quarters 0,1 in flight under coef setup
    issue(bufB, 1);

    // M = Rz(b)*Ry(a) = [cb*ca, -sb, cb*sa; sb*ca, cb, sb*sa; -sa, 0, ca]
    if (tid < WSZ) {
        float2 th = reinterpret_cast<const float2*>(theta)[tid];
        float sa = __builtin_amdgcn_sinf(th.x * INV2PI);
        float ca = __builtin_amdgcn_cosf(th.x * INV2PI);
        float sb = __builtin_amdgcn_sinf(th.y * INV2PI);
        float cb = __builtin_amdgcn_cosf(th.y * INV2PI);
        tA[tid] = make_float4(cb * ca, -sb, cb * sa, sb * ca);
        tB[tid] = make_float4(cb, sb * sa, -sa, ca);
    }
    __syncthreads();             // only barrier in the kernel

    float vx = 0.0f, vy = 0.0f, vz = 1.0f;

    // 16 steps from one buffer. sched_barrier(0) caps the scheduler's
    // ds_read-hoisting window (R7's spill mechanism: 140 VGPR + 38MB scratch).
    auto quarter = [&](float4 (&b)[4], int g) {
        __builtin_amdgcn_sched_barrier(0);
        #pragma unroll
        for (int c = 0; c < 4; ++c) {
            float q[4] = {b[c].x, b[c].y, b[c].z, b[c].w};
            #pragma unroll
            for (int j = 0; j < 4; ++j) {
                const int t = g * 16 + c * 4 + j;    // uniform LDS index
                float r  = q[j] * INV2PI;            // q[j]: compile-time select
                float s  = __builtin_amdgcn_sinf(r);
                float co = __builtin_amdgcn_cosf(r);
                float4 A  = tA[t];                   // uniform ds_read_b128 broadcast
                float4 Bv = tB[t];
                float y1 = co * vy - s  * vz;        // Rx(x_t)
                float z1 = s  * vy + co * vz;
                float nx = A.x  * vx + A.y  * y1 + A.z  * z1;
                float ny = A.w  * vx + Bv.x * y1 + Bv.y * z1;
                float nz = Bv.z * vx + Bv.w * z1;    // m21 == 0
                vx = nx; vy = ny; vz = nz;
            }
        }
    };

    quarter(bufA, 0);
    issue(bufA, 2);              // refill flies under quarter 1's compute
    quarter(bufB, 1);
    issue(bufB, 3);              // refill flies under quarter 2's compute
    quarter(bufA, 2);
    quarter(bufB, 3);

    out[row] = vz * wv + bv;
}

extern "C" void kernel_launch(void* const* d_in, const int* in_sizes, int n_in,
                              void* d_out, int out_size, void* d_ws, size_t ws_size,
                              hipStream_t stream) {
    const float* x     = (const float*)d_in[0];
    const float* theta = (const float*)d_in[1];
    const float* w     = (const float*)d_in[2];
    const float* b     = (const float*)d_in[3];
    float* out = (float*)d_out;

    int nrows = out_size;                 // B = 524288 (divisible by 256)
    int grid  = nrows / BLOCK;            // 2048 blocks
    sq_main<<<grid, BLOCK, 0, stream>>>(x, theta, w, b, out);
}